// Round 3
// baseline (510.383 us; speedup 1.0000x reference)
//
#include <hip/hip_runtime.h>
#include <cstdint>
#include <cstddef>

#define BZ 4
#define CD 96
#define LL 9216
#define DD 192
#define NS 16
#define RR 6
#define LC 32
#define NG 288
#define MTOK (BZ * LL)

#define SA 256.0f
#define SW 1024.0f
#define SY 16.0f

typedef _Float16 f16x8 __attribute__((ext_vector_type(8)));
typedef _Float16 f16x4 __attribute__((ext_vector_type(4)));
typedef float f32x4 __attribute__((ext_vector_type(4)));

__device__ __forceinline__ float siluf(float x) {
    return x / (1.f + __expf(-x));
}
__device__ __forceinline__ float softplusf(float x) {
    return fmaxf(x, 0.f) + log1pf(__expf(-fabsf(x)));
}

// ---------------------------------------------------------------------------
// Fold LN gain/bias into projection weights (fp32 staging for the splitter):
// gw[d,c] = ln_g[c]*w[d,c];  wsum[d] = sum_c gw[d,c];  bias[d] = b[d] + sum_c ln_b[c]*w[d,c]
__global__ void prep_kernel(const float* kg, const float* kb, const float* kw, const float* kbias,
                            const float* qg, const float* qb, const float* qw, const float* qbias,
                            float* gwK, float* wsumK, float* biasK,
                            float* gwQ, float* wsumQ, float* biasQ) {
    int d = blockIdx.x;
    const float* g  = blockIdx.y ? qg : kg;
    const float* lb = blockIdx.y ? qb : kb;
    const float* w  = blockIdx.y ? qw : kw;
    const float* b2 = blockIdx.y ? qbias : kbias;
    float* gw = blockIdx.y ? gwQ : gwK;
    float* wsv = blockIdx.y ? wsumQ : wsumK;
    float* bv = blockIdx.y ? biasQ : biasK;
    int c = threadIdx.x;
    __shared__ float s1[96], s2[96];
    float wv = w[d * 96 + c];
    float gv = g[c] * wv;
    gw[d * 96 + c] = gv;
    s1[c] = gv;
    s2[c] = lb[c] * wv;
    __syncthreads();
    if (c < 32) { s1[c] += s1[c + 64]; s2[c] += s2[c + 64]; }
    __syncthreads();
    for (int s = 32; s >= 1; s >>= 1) {
        if (c < s) { s1[c] += s1[c + s]; s2[c] += s2[c + s]; }
        __syncthreads();
    }
    if (c == 0) { wsv[d] = s1[0]; bv[d] = b2[d] + s2[0]; }
}

// ---------------------------------------------------------------------------
// One fused kernel splitting all six weight matrices into hi/lo f16 planes (x SW).
// Segment table hardcoded: sizes in elements of the PADDED destination.
__global__ __launch_bounds__(256) void split_all_kernel(
    const float* __restrict__ s0, const float* __restrict__ s1, const float* __restrict__ s2,
    const float* __restrict__ s3, const float* __restrict__ s4, const float* __restrict__ s5,
    _Float16* __restrict__ d0h, _Float16* __restrict__ d0l,
    _Float16* __restrict__ d1h, _Float16* __restrict__ d1l,
    _Float16* __restrict__ d2h, _Float16* __restrict__ d2l,
    _Float16* __restrict__ d3h, _Float16* __restrict__ d3l,
    _Float16* __restrict__ d4h, _Float16* __restrict__ d4l,
    _Float16* __restrict__ d5h, _Float16* __restrict__ d5l)
{
    int idx = blockIdx.x * 256 + threadIdx.x;
    const int C0 = 18432, C1 = 18432, C2 = 18432, C3 = 18432, C4 = 73728, C5 = 18432;
    const float* src; _Float16* dh; _Float16* dl; int i; bool pad = false;
    if (idx < C0) { src = s0; dh = d0h; dl = d0l; i = idx; }
    else if (idx < C0 + C1) { src = s1; dh = d1h; dl = d1l; i = idx - C0; }
    else if (idx < C0 + C1 + C2) { src = s2; dh = d2h; dl = d2l; i = idx - C0 - C1; }
    else if (idx < C0 + C1 + C2 + C3) {
        src = s3; dh = d3h; dl = d3l; i = idx - C0 - C1 - C2;
        pad = (i / 384) >= 38;   // dtbc_w: 38 real rows padded to 48
    }
    else if (idx < C0 + C1 + C2 + C3 + C4) { src = s4; dh = d4h; dl = d4l; i = idx - C0 - C1 - C2 - C3; }
    else if (idx < C0 + C1 + C2 + C3 + C4 + C5) { src = s5; dh = d5h; dl = d5l; i = idx - C0 - C1 - C2 - C3 - C4; }
    else return;
    float v = pad ? 0.f : src[i] * SW;
    _Float16 h = (_Float16)v;
    dh[i] = h;
    dl[i] = (_Float16)(v - (float)h);
}

// ---------------------------------------------------------------------------
// MFMA projection from channel-major (B,C,L) input, K=96, N=192.
// LN variant: fused per-token LN stats (from staged tile) + folded-LN epilogue
// + silu + split f16 output. !LN: plain fp32 output (xin for conv).
template<bool LN>
__global__ __launch_bounds__(256) void mfma_projCH(
    const float* __restrict__ A,
    const _Float16* __restrict__ Wh, const _Float16* __restrict__ Wl,
    const float* __restrict__ wsum, const float* __restrict__ biasv,
    float* __restrict__ outF,
    _Float16* __restrict__ outH, _Float16* __restrict__ outL)
{
    int b = blockIdx.y;
    int l0 = blockIdx.x * 64;
    int tid = threadIdx.x;
    int lane = tid & 63, w = tid >> 6;
    __shared__ __align__(16) _Float16 Ah[64 * 104];
    __shared__ __align__(16) _Float16 Al[64 * 104];
    __shared__ float sm[64], siv[64];
    __shared__ float red1[256], red2[256];
    for (int i = tid; i < 96 * 64; i += 256) {
        int c = i >> 6, l = i & 63;
        float v = A[((size_t)b * CD + c) * LL + l0 + l] * SA;
        _Float16 h = (_Float16)v;
        Ah[l * 104 + c] = h;
        Al[l * 104 + c] = (_Float16)(v - (float)h);
    }
    __syncthreads();
    if (LN) {
        int tl = tid >> 2, p = tid & 3;
        float s = 0.f, ss = 0.f;
        for (int j = 0; j < 24; j++) {
            int c = p * 24 + j;
            float v = ((float)Ah[tl * 104 + c] + (float)Al[tl * 104 + c]) * (1.f / SA);
            s += v; ss += v * v;
        }
        red1[tid] = s; red2[tid] = ss;
        __syncthreads();
        if (tid < 64) {
            float s4 = red1[tid * 4] + red1[tid * 4 + 1] + red1[tid * 4 + 2] + red1[tid * 4 + 3];
            float q4 = red2[tid * 4] + red2[tid * 4 + 1] + red2[tid * 4 + 2] + red2[tid * 4 + 3];
            float m = s4 / 96.f;
            sm[tid] = m;
            siv[tid] = rsqrtf(fmaxf(q4 / 96.f - m * m, 0.f) + 1e-5f);
        }
        __syncthreads();
    }
    int col = lane & 15, quad = lane >> 4;
    int n0 = w * 48;
    f32x4 zv4 = {0.f, 0.f, 0.f, 0.f};
    f32x4 acc[4][3];
    #pragma unroll
    for (int mi = 0; mi < 4; mi++)
        #pragma unroll
        for (int ni = 0; ni < 3; ni++) acc[mi][ni] = zv4;
    for (int c0 = 0; c0 < 96; c0 += 32) {
        f16x8 afh[4], afl[4], bfh[3], bfl[3];
        #pragma unroll
        for (int mi = 0; mi < 4; mi++) {
            int off = (16 * mi + col) * 104 + c0 + quad * 8;
            afh[mi] = *(const f16x8*)&Ah[off];
            afl[mi] = *(const f16x8*)&Al[off];
        }
        #pragma unroll
        for (int ni = 0; ni < 3; ni++) {
            size_t off = (size_t)(n0 + ni * 16 + col) * 96 + c0 + quad * 8;
            bfh[ni] = *(const f16x8*)&Wh[off];
            bfl[ni] = *(const f16x8*)&Wl[off];
        }
        #pragma unroll
        for (int mi = 0; mi < 4; mi++)
            #pragma unroll
            for (int ni = 0; ni < 3; ni++) {
                acc[mi][ni] = __builtin_amdgcn_mfma_f32_16x16x32_f16(afh[mi], bfl[ni], acc[mi][ni], 0, 0, 0);
                acc[mi][ni] = __builtin_amdgcn_mfma_f32_16x16x32_f16(afl[mi], bfh[ni], acc[mi][ni], 0, 0, 0);
                acc[mi][ni] = __builtin_amdgcn_mfma_f32_16x16x32_f16(afh[mi], bfh[ni], acc[mi][ni], 0, 0, 0);
            }
    }
    const float isc = 1.f / (SA * SW);
    #pragma unroll
    for (int ni = 0; ni < 3; ni++) {
        int d = n0 + ni * 16 + col;
        float wsv = LN ? wsum[d] : 0.f;
        float bvv = LN ? biasv[d] : 0.f;
        #pragma unroll
        for (int mi = 0; mi < 4; mi++)
            #pragma unroll
            for (int r = 0; r < 4; r++) {
                int tl = mi * 16 + quad * 4 + r;
                float v = acc[mi][ni][r] * isc;
                size_t t = (size_t)b * LL + l0 + tl;
                if (LN) {
                    v = (v - sm[tl] * wsv) * siv[tl] + bvv;
                    v = siluf(v) * SA;
                    _Float16 h = (_Float16)v;
                    outH[t * DD + d] = h;
                    outL[t * DD + d] = (_Float16)(v - (float)h);
                } else {
                    outF[t * DD + d] = v;
                }
            }
    }
}

// ---------------------------------------------------------------------------
// Depthwise causal conv (k=4) + bias + silu -> split f16 u planes (x SA).
// Register-tiled: 4 tokens x 4 dims per thread, float4 loads, f16x4 stores.
__global__ __launch_bounds__(256) void conv_kernel(const float* __restrict__ xin,
        const float* __restrict__ cw, const float* __restrict__ cb,
        _Float16* __restrict__ uh, _Float16* __restrict__ ul)
{
    int gid = blockIdx.x * 256 + threadIdx.x;        // [0, (MTOK/4)*(DD/4))
    int dg = gid % (DD / 4);
    int tg = gid / (DD / 4);
    int b = tg / (LL / 4);
    int l0 = (tg % (LL / 4)) * 4;
    size_t rowbase = ((size_t)b * LL + l0) * DD + dg * 4;
    f32x4 r[7];
    #pragma unroll
    for (int j = 0; j < 7; j++) {
        int l = l0 - 3 + j;
        f32x4 z4 = {0.f, 0.f, 0.f, 0.f};
        r[j] = (l >= 0) ? *(const f32x4*)&xin[rowbase + (size_t)(j - 3) * DD] : z4;
    }
    float cwv[4][4], cb4[4];
    #pragma unroll
    for (int e = 0; e < 4; e++) {
        cb4[e] = cb[dg * 4 + e];
        #pragma unroll
        for (int j = 0; j < 4; j++) cwv[e][j] = cw[(dg * 4 + e) * 4 + j];
    }
    #pragma unroll
    for (int tt = 0; tt < 4; tt++) {
        f16x4 oh, ol;
        #pragma unroll
        for (int e = 0; e < 4; e++) {
            float s = cb4[e];
            #pragma unroll
            for (int j = 0; j < 4; j++) s = fmaf(cwv[e][j], r[tt + j][e], s);
            float u = siluf(s) * SA;
            _Float16 h = (_Float16)u;
            oh[e] = h;
            ol[e] = (_Float16)(u - (float)h);
        }
        *(f16x4*)&uh[rowbase + (size_t)tt * DD] = oh;
        *(f16x4*)&ul[rowbase + (size_t)tt * DD] = ol;
    }
}

// ---------------------------------------------------------------------------
// Token-major MFMA GEMM on f16x2 split planes.
// EPI: 0 = silu fp32 (z-gate), 1 = routed store into dtb/Bb/Cb (xdbl),
//      2 = transposed fp32 float4 store (final out, (B,C,L)).
template<int BR, int BC, int KD, int EPI>
__global__ __launch_bounds__(256) void mfma_gemm_tok(
    const _Float16* __restrict__ A0h, const _Float16* __restrict__ A0l,
    const _Float16* __restrict__ A1h, const _Float16* __restrict__ A1l,
    const _Float16* __restrict__ Wh, const _Float16* __restrict__ Wl,
    const float* __restrict__ bias, float oscale, float* __restrict__ outF,
    float* __restrict__ dtbp, float* __restrict__ Bbp, float* __restrict__ Cbp)
{
    int tid = threadIdx.x;
    int lane = tid & 63, w = tid >> 6;
    int mr = w % BR, nc = w / BR;
    int t0 = blockIdx.x * (BR * 64) + mr * 64;
    int n0 = nc * 48;
    int col = lane & 15, quad = lane >> 4;
    f32x4 zv4 = {0.f, 0.f, 0.f, 0.f};
    f32x4 acc[4][3];
    #pragma unroll
    for (int mi = 0; mi < 4; mi++)
        #pragma unroll
        for (int ni = 0; ni < 3; ni++) acc[mi][ni] = zv4;
    for (int k0 = 0; k0 < KD; k0 += 32) {
        const _Float16* Ah = (KD == 384 && k0 >= 192) ? A1h : A0h;
        const _Float16* Al = (KD == 384 && k0 >= 192) ? A1l : A0l;
        int kc = (KD == 384 && k0 >= 192) ? k0 - 192 : k0;
        f16x8 afh[4], afl[4], bfh[3], bfl[3];
        #pragma unroll
        for (int mi = 0; mi < 4; mi++) {
            size_t off = (size_t)(t0 + mi * 16 + col) * DD + kc + quad * 8;
            afh[mi] = *(const f16x8*)&Ah[off];
            afl[mi] = *(const f16x8*)&Al[off];
        }
        #pragma unroll
        for (int ni = 0; ni < 3; ni++) {
            size_t off = (size_t)(n0 + ni * 16 + col) * KD + k0 + quad * 8;
            bfh[ni] = *(const f16x8*)&Wh[off];
            bfl[ni] = *(const f16x8*)&Wl[off];
        }
        #pragma unroll
        for (int mi = 0; mi < 4; mi++)
            #pragma unroll
            for (int ni = 0; ni < 3; ni++) {
                acc[mi][ni] = __builtin_amdgcn_mfma_f32_16x16x32_f16(afh[mi], bfl[ni], acc[mi][ni], 0, 0, 0);
                acc[mi][ni] = __builtin_amdgcn_mfma_f32_16x16x32_f16(afl[mi], bfh[ni], acc[mi][ni], 0, 0, 0);
                acc[mi][ni] = __builtin_amdgcn_mfma_f32_16x16x32_f16(afh[mi], bfh[ni], acc[mi][ni], 0, 0, 0);
            }
    }
    if (EPI == 2) {
        int bq = t0 / LL;
        int lb = t0 % LL;
        #pragma unroll
        for (int ni = 0; ni < 3; ni++) {
            int d = n0 + ni * 16 + col;
            #pragma unroll
            for (int mi = 0; mi < 4; mi++) {
                f32x4 v;
                #pragma unroll
                for (int r = 0; r < 4; r++) v[r] = acc[mi][ni][r] * oscale;
                *(f32x4*)&outF[((size_t)(bq * 96 + d)) * LL + lb + mi * 16 + quad * 4] = v;
            }
        }
    } else if (EPI == 1) {
        #pragma unroll
        for (int ni = 0; ni < 3; ni++) {
            int d = n0 + ni * 16 + col;
            #pragma unroll
            for (int mi = 0; mi < 4; mi++)
                #pragma unroll
                for (int r = 0; r < 4; r++) {
                    size_t t = t0 + mi * 16 + quad * 4 + r;
                    float v = acc[mi][ni][r] * oscale;
                    if (d < 6)       dtbp[t * 8 + d] = v;
                    else if (d < 22) Bbp[t * 16 + (d - 6)] = v;
                    else if (d < 38) Cbp[t * 16 + (d - 22)] = v;
                    else if (d < 40) dtbp[t * 8 + (d - 32)] = 0.f;
                }
        }
    } else {
        #pragma unroll
        for (int ni = 0; ni < 3; ni++) {
            int d = n0 + ni * 16 + col;
            float bv = bias[d];
            #pragma unroll
            for (int mi = 0; mi < 4; mi++)
                #pragma unroll
                for (int r = 0; r < 4; r++) {
                    size_t t = t0 + mi * 16 + quad * 4 + r;
                    float v = acc[mi][ni][r] * oscale;
                    outF[t * DD + d] = siluf(v + bv);
                }
        }
    }
}

// ---------------------------------------------------------------------------
// Chunked selective scan. No LDS, no barriers. dt/B/C read as wave-uniform
// f32x4 global loads from the routed buffers. delta fused.
__global__ __launch_bounds__(64) void scan_pass1(
    const _Float16* __restrict__ uh, const _Float16* __restrict__ ul,
    const float* __restrict__ dtb, const float* __restrict__ Bb,
    const float* __restrict__ A_log,
    const float* __restrict__ dtw, const float* __restrict__ dtbias,
    float* __restrict__ P_ws, float* __restrict__ S_ws)
{
    int g = blockIdx.x, dblk = blockIdx.y, b = blockIdx.z;
    int d = dblk * 64 + threadIdx.x;
    size_t tbase = (size_t)b * LL + g * LC;
    float Av[NS];
    #pragma unroll
    for (int n = 0; n < NS; n++) Av[n] = -__expf(A_log[d * NS + n]);
    float w6[RR];
    #pragma unroll
    for (int r = 0; r < RR; r++) w6[r] = dtw[d * RR + r];
    float b2 = 2.f * dtbias[d];
    float h[NS];
    #pragma unroll
    for (int n = 0; n < NS; n++) h[n] = 0.f;
    float sd = 0.f;
    const _Float16* uhp = uh + tbase * DD + d;
    const _Float16* ulp = ul + tbase * DD + d;
    #pragma unroll 2
    for (int t = 0; t < LC; t++) {
        f32x4 d0 = *(const f32x4*)&dtb[(tbase + t) * 8];
        f32x4 d1 = *(const f32x4*)&dtb[(tbase + t) * 8 + 4];
        float s = b2;
        s = fmaf(d0[0], w6[0], s); s = fmaf(d0[1], w6[1], s);
        s = fmaf(d0[2], w6[2], s); s = fmaf(d0[3], w6[3], s);
        s = fmaf(d1[0], w6[4], s); s = fmaf(d1[1], w6[5], s);
        float dlt = softplusf(s);
        sd += dlt;
        float uu = ((float)uhp[(size_t)t * DD] + (float)ulp[(size_t)t * DD]) * (1.f / SA);
        float du = dlt * uu;
        f32x4 Bv[4];
        #pragma unroll
        for (int q = 0; q < 4; q++) Bv[q] = *(const f32x4*)&Bb[(tbase + t) * 16 + q * 4];
        #pragma unroll
        for (int n = 0; n < NS; n++) {
            float a = __expf(dlt * Av[n]);
            h[n] = fmaf(a, h[n], du * Bv[n >> 2][n & 3]);
        }
    }
    size_t o = ((size_t)(b * NG + g) * DD + d) * NS;
    #pragma unroll
    for (int q = 0; q < 4; q++) {
        f32x4 pv, sv;
        #pragma unroll
        for (int e = 0; e < 4; e++) {
            pv[e] = __expf(sd * Av[q * 4 + e]);
            sv[e] = h[q * 4 + e];
        }
        *(f32x4*)(P_ws + o + q * 4) = pv;
        *(f32x4*)(S_ws + o + q * 4) = sv;
    }
}

__global__ __launch_bounds__(256) void scan_combine(const float* __restrict__ P_ws,
        const float* __restrict__ S_ws, float* __restrict__ H_ws)
{
    int idx = blockIdx.x * 256 + threadIdx.x;
    int b = idx / (DD * NS);
    int r = idx % (DD * NS);
    size_t base = (size_t)b * NG * DD * NS + r;
    float h = 0.f;
    #pragma unroll 16
    for (int g = 0; g < NG; g++) {
        size_t o = base + (size_t)g * DD * NS;
        H_ws[o] = h;
        h = fmaf(P_ws[o], h, S_ws[o]);
    }
}

__global__ __launch_bounds__(64) void scan_pass2(
    const _Float16* __restrict__ uh, const _Float16* __restrict__ ul,
    const float* __restrict__ dtb, const float* __restrict__ Bb,
    const float* __restrict__ Cb, const float* __restrict__ A_log,
    const float* __restrict__ dtw, const float* __restrict__ dtbias,
    const float* __restrict__ H_ws, const float* __restrict__ zs,
    const float* __restrict__ Dvec,
    _Float16* __restrict__ yh, _Float16* __restrict__ yl)
{
    int g = blockIdx.x, dblk = blockIdx.y, b = blockIdx.z;
    int d = dblk * 64 + threadIdx.x;
    size_t tbase = (size_t)b * LL + g * LC;
    float Av[NS];
    #pragma unroll
    for (int n = 0; n < NS; n++) Av[n] = -__expf(A_log[d * NS + n]);
    float w6[RR];
    #pragma unroll
    for (int r = 0; r < RR; r++) w6[r] = dtw[d * RR + r];
    float b2 = 2.f * dtbias[d];
    float h[NS];
    size_t o = ((size_t)(b * NG + g) * DD + d) * NS;
    #pragma unroll
    for (int q = 0; q < 4; q++) {
        f32x4 hv = *(const f32x4*)(H_ws + o + q * 4);
        #pragma unroll
        for (int e = 0; e < 4; e++) h[q * 4 + e] = hv[e];
    }
    float Dv = Dvec[d];
    const _Float16* uhp = uh + tbase * DD + d;
    const _Float16* ulp = ul + tbase * DD + d;
    const float* zp = zs + tbase * DD + d;
    _Float16* yhp = yh + tbase * DD + d;
    _Float16* ylp = yl + tbase * DD + d;
    #pragma unroll 2
    for (int t = 0; t < LC; t++) {
        f32x4 d0 = *(const f32x4*)&dtb[(tbase + t) * 8];
        f32x4 d1 = *(const f32x4*)&dtb[(tbase + t) * 8 + 4];
        float s = b2;
        s = fmaf(d0[0], w6[0], s); s = fmaf(d0[1], w6[1], s);
        s = fmaf(d0[2], w6[2], s); s = fmaf(d0[3], w6[3], s);
        s = fmaf(d1[0], w6[4], s); s = fmaf(d1[1], w6[5], s);
        float dlt = softplusf(s);
        float uu = ((float)uhp[(size_t)t * DD] + (float)ulp[(size_t)t * DD]) * (1.f / SA);
        float du = dlt * uu;
        f32x4 Bv[4], Cv[4];
        #pragma unroll
        for (int q = 0; q < 4; q++) {
            Bv[q] = *(const f32x4*)&Bb[(tbase + t) * 16 + q * 4];
            Cv[q] = *(const f32x4*)&Cb[(tbase + t) * 16 + q * 4];
        }
        float yv = 0.f;
        #pragma unroll
        for (int n = 0; n < NS; n++) {
            float a = __expf(dlt * Av[n]);
            h[n] = fmaf(a, h[n], du * Bv[n >> 2][n & 3]);
            yv = fmaf(h[n], Cv[n >> 2][n & 3], yv);
        }
        float zv = zp[(size_t)t * DD];
        float y = (yv + uu * Dv) * zv * SY;
        _Float16 hh = (_Float16)y;
        yhp[(size_t)t * DD] = hh;
        ylp[(size_t)t * DD] = (_Float16)(y - (float)hh);
    }
}

// ---------------------------------------------------------------------------
extern "C" void kernel_launch(void* const* d_in, const int* in_sizes, int n_in,
                              void* d_out, int out_size, void* d_ws, size_t ws_size,
                              hipStream_t stream)
{
    (void)in_sizes; (void)n_in; (void)out_size; (void)ws_size;
    const float* x        = (const float*)d_in[0];
    const float* K        = (const float*)d_in[1];
    const float* Q        = (const float*)d_in[2];
    const float* in_projw = (const float*)d_in[3];
    const float* conv_w   = (const float*)d_in[4];
    const float* conv_b   = (const float*)d_in[5];
    const float* k_ln_g   = (const float*)d_in[6];
    const float* k_ln_b   = (const float*)d_in[7];
    const float* k_w      = (const float*)d_in[8];
    const float* k_b      = (const float*)d_in[9];
    const float* q_ln_g   = (const float*)d_in[10];
    const float* q_ln_b   = (const float*)d_in[11];
    const float* q_w      = (const float*)d_in[12];
    const float* q_b      = (const float*)d_in[13];
    const float* dtbc_w   = (const float*)d_in[14];
    const float* dt_w     = (const float*)d_in[15];
    const float* dt_b     = (const float*)d_in[16];
    const float* gate_w   = (const float*)d_in[17];
    const float* gate_b   = (const float*)d_in[18];
    const float* A_log    = (const float*)d_in[19];
    const float* Dvec     = (const float*)d_in[20];
    const float* out_w    = (const float*)d_in[21];
    float* out = (float*)d_out;

    const size_t S0 = (size_t)MTOK * DD;
    char* base = (char*)d_ws;
    size_t off = 0;
    auto alloc = [&](size_t bytes) {
        char* p = base + off;
        off += (bytes + 255) & ~(size_t)255;
        return p;
    };
    float*     xin   = (float*)alloc(S0 * 4);            // reused as zs
    _Float16*  uH    = (_Float16*)alloc(S0 * 2);
    _Float16*  uL    = (_Float16*)alloc(S0 * 2);
    _Float16*  KpH   = (_Float16*)alloc(S0 * 2);         // reused as yH
    _Float16*  KpL   = (_Float16*)alloc(S0 * 2);         // reused as yL
    _Float16*  QpH   = (_Float16*)alloc(S0 * 2);
    _Float16*  QpL   = (_Float16*)alloc(S0 * 2);
    float*     dtbB  = (float*)alloc((size_t)MTOK * 8 * 4);
    float*     Bb    = (float*)alloc((size_t)MTOK * 16 * 4);
    float*     Cb    = (float*)alloc((size_t)MTOK * 16 * 4);
    float*     gwK   = (float*)alloc(DD * CD * 4);
    float*     gwQ   = (float*)alloc(DD * CD * 4);
    float*     wsumK = (float*)alloc(DD * 4);
    float*     biasK = (float*)alloc(DD * 4);
    float*     wsumQ = (float*)alloc(DD * 4);
    float*     biasQ = (float*)alloc(DD * 4);
    _Float16*  ipWh  = (_Float16*)alloc(DD * CD * 2);
    _Float16*  ipWl  = (_Float16*)alloc(DD * CD * 2);
    _Float16*  kWh   = (_Float16*)alloc(DD * CD * 2);
    _Float16*  kWl   = (_Float16*)alloc(DD * CD * 2);
    _Float16*  qWh   = (_Float16*)alloc(DD * CD * 2);
    _Float16*  qWl   = (_Float16*)alloc(DD * CD * 2);
    _Float16*  dbWh  = (_Float16*)alloc(48 * 384 * 2);
    _Float16*  dbWl  = (_Float16*)alloc(48 * 384 * 2);
    _Float16*  gWh   = (_Float16*)alloc(DD * 384 * 2);
    _Float16*  gWl   = (_Float16*)alloc(DD * 384 * 2);
    _Float16*  oWh   = (_Float16*)alloc(96 * DD * 2);
    _Float16*  oWl   = (_Float16*)alloc(96 * DD * 2);
    float*     P_ws  = (float*)alloc((size_t)BZ * NG * DD * NS * 4);
    float*     S_ws  = (float*)alloc((size_t)BZ * NG * DD * NS * 4);
    float*     H_ws  = (float*)alloc((size_t)BZ * NG * DD * NS * 4);
    float*    zs = xin;
    _Float16* yH = KpH;
    _Float16* yL = KpL;

    prep_kernel<<<dim3(DD, 2), 96, 0, stream>>>(k_ln_g, k_ln_b, k_w, k_b,
        q_ln_g, q_ln_b, q_w, q_b, gwK, wsumK, biasK, gwQ, wsumQ, biasQ);
    {
        const int total = 18432 * 5 + 73728;
        split_all_kernel<<<(total + 255) / 256, 256, 0, stream>>>(
            in_projw, gwK, gwQ, dtbc_w, gate_w, out_w,
            ipWh, ipWl, kWh, kWl, qWh, qWl, dbWh, dbWl, gWh, gWl, oWh, oWl);
    }

    mfma_projCH<false><<<dim3(LL / 64, BZ), 256, 0, stream>>>(
        x, ipWh, ipWl, nullptr, nullptr, xin, nullptr, nullptr);
    mfma_projCH<true><<<dim3(LL / 64, BZ), 256, 0, stream>>>(
        K, kWh, kWl, wsumK, biasK, nullptr, KpH, KpL);
    mfma_projCH<true><<<dim3(LL / 64, BZ), 256, 0, stream>>>(
        Q, qWh, qWl, wsumQ, biasQ, nullptr, QpH, QpL);
    conv_kernel<<<(MTOK / 4) * (DD / 4) / 256, 256, 0, stream>>>(xin, conv_w, conv_b, uH, uL);
    mfma_gemm_tok<4, 1, 384, 1><<<MTOK / 256, 256, 0, stream>>>(
        uH, uL, KpH, KpL, dbWh, dbWl, nullptr, 1.f / (SA * SW), nullptr, dtbB, Bb, Cb);
    mfma_gemm_tok<1, 4, 384, 0><<<MTOK / 64, 256, 0, stream>>>(
        uH, uL, QpH, QpL, gWh, gWl, gate_b, 1.f / (SA * SW), zs, nullptr, nullptr, nullptr);
    scan_pass1<<<dim3(NG, DD / 64, BZ), 64, 0, stream>>>(
        uH, uL, dtbB, Bb, A_log, dt_w, dt_b, P_ws, S_ws);
    scan_combine<<<(BZ * DD * NS) / 256, 256, 0, stream>>>(P_ws, S_ws, H_ws);
    scan_pass2<<<dim3(NG, DD / 64, BZ), 64, 0, stream>>>(
        uH, uL, dtbB, Bb, Cb, A_log, dt_w, dt_b, H_ws, zs, Dvec, yH, yL);
    mfma_gemm_tok<2, 2, 192, 2><<<MTOK / 128, 256, 0, stream>>>(
        yH, yL, nullptr, nullptr, oWh, oWl, nullptr, 1.f / (SY * SW), out, nullptr, nullptr, nullptr);
}

// Round 4
// 425.332 us; speedup vs baseline: 1.2000x; 1.2000x over previous
//
#include <hip/hip_runtime.h>
#include <cstdint>
#include <cstddef>

#define BZ 4
#define CD 96
#define LL 9216
#define DD 192
#define NS 16
#define RR 6
#define LC 32
#define NG 288
#define NGRP 16
#define GSZ 18
#define MTOK (BZ * LL)

#define SA 256.0f
#define SW 1024.0f
#define SY 16.0f

typedef _Float16 f16x8 __attribute__((ext_vector_type(8)));
typedef _Float16 f16x4 __attribute__((ext_vector_type(4)));
typedef float f32x4 __attribute__((ext_vector_type(4)));

__device__ __forceinline__ float siluf(float x) {
    return x / (1.f + __expf(-x));
}
__device__ __forceinline__ float softplusf(float x) {
    return fmaxf(x, 0.f) + log1pf(__expf(-fabsf(x)));
}

// ---------------------------------------------------------------------------
// Fold LN gain/bias into projection weights (fp32 staging for the splitter):
// gw[d,c] = ln_g[c]*w[d,c];  wsum[d] = sum_c gw[d,c];  bias[d] = b[d] + sum_c ln_b[c]*w[d,c]
__global__ void prep_kernel(const float* kg, const float* kb, const float* kw, const float* kbias,
                            const float* qg, const float* qb, const float* qw, const float* qbias,
                            float* gwK, float* wsumK, float* biasK,
                            float* gwQ, float* wsumQ, float* biasQ) {
    int d = blockIdx.x;
    const float* g  = blockIdx.y ? qg : kg;
    const float* lb = blockIdx.y ? qb : kb;
    const float* w  = blockIdx.y ? qw : kw;
    const float* b2 = blockIdx.y ? qbias : kbias;
    float* gw = blockIdx.y ? gwQ : gwK;
    float* wsv = blockIdx.y ? wsumQ : wsumK;
    float* bv = blockIdx.y ? biasQ : biasK;
    int c = threadIdx.x;
    __shared__ float s1[96], s2[96];
    float wv = w[d * 96 + c];
    float gv = g[c] * wv;
    gw[d * 96 + c] = gv;
    s1[c] = gv;
    s2[c] = lb[c] * wv;
    __syncthreads();
    if (c < 32) { s1[c] += s1[c + 64]; s2[c] += s2[c + 64]; }
    __syncthreads();
    for (int s = 32; s >= 1; s >>= 1) {
        if (c < s) { s1[c] += s1[c + s]; s2[c] += s2[c + s]; }
        __syncthreads();
    }
    if (c == 0) { wsv[d] = s1[0]; bv[d] = b2[d] + s2[0]; }
}

// ---------------------------------------------------------------------------
// One fused kernel splitting all six weight matrices into hi/lo f16 planes (x SW).
__global__ __launch_bounds__(256) void split_all_kernel(
    const float* __restrict__ s0, const float* __restrict__ s1, const float* __restrict__ s2,
    const float* __restrict__ s3, const float* __restrict__ s4, const float* __restrict__ s5,
    _Float16* __restrict__ d0h, _Float16* __restrict__ d0l,
    _Float16* __restrict__ d1h, _Float16* __restrict__ d1l,
    _Float16* __restrict__ d2h, _Float16* __restrict__ d2l,
    _Float16* __restrict__ d3h, _Float16* __restrict__ d3l,
    _Float16* __restrict__ d4h, _Float16* __restrict__ d4l,
    _Float16* __restrict__ d5h, _Float16* __restrict__ d5l)
{
    int idx = blockIdx.x * 256 + threadIdx.x;
    const int C0 = 18432, C1 = 18432, C2 = 18432, C3 = 18432, C4 = 73728, C5 = 18432;
    const float* src; _Float16* dh; _Float16* dl; int i; bool pad = false;
    if (idx < C0) { src = s0; dh = d0h; dl = d0l; i = idx; }
    else if (idx < C0 + C1) { src = s1; dh = d1h; dl = d1l; i = idx - C0; }
    else if (idx < C0 + C1 + C2) { src = s2; dh = d2h; dl = d2l; i = idx - C0 - C1; }
    else if (idx < C0 + C1 + C2 + C3) {
        src = s3; dh = d3h; dl = d3l; i = idx - C0 - C1 - C2;
        pad = (i / 384) >= 38;   // dtbc_w: 38 real rows padded to 48
    }
    else if (idx < C0 + C1 + C2 + C3 + C4) { src = s4; dh = d4h; dl = d4l; i = idx - C0 - C1 - C2 - C3; }
    else if (idx < C0 + C1 + C2 + C3 + C4 + C5) { src = s5; dh = d5h; dl = d5l; i = idx - C0 - C1 - C2 - C3 - C4; }
    else return;
    float v = pad ? 0.f : src[i] * SW;
    _Float16 h = (_Float16)v;
    dh[i] = h;
    dl[i] = (_Float16)(v - (float)h);
}

// ---------------------------------------------------------------------------
// MFMA projection from channel-major (B,C,L) input, K=96, N=192.
template<bool LN>
__global__ __launch_bounds__(256) void mfma_projCH(
    const float* __restrict__ A,
    const _Float16* __restrict__ Wh, const _Float16* __restrict__ Wl,
    const float* __restrict__ wsum, const float* __restrict__ biasv,
    float* __restrict__ outF,
    _Float16* __restrict__ outH, _Float16* __restrict__ outL)
{
    int b = blockIdx.y;
    int l0 = blockIdx.x * 64;
    int tid = threadIdx.x;
    int lane = tid & 63, w = tid >> 6;
    __shared__ __align__(16) _Float16 Ah[64 * 104];
    __shared__ __align__(16) _Float16 Al[64 * 104];
    __shared__ float sm[64], siv[64];
    __shared__ float red1[256], red2[256];
    for (int i = tid; i < 96 * 64; i += 256) {
        int c = i >> 6, l = i & 63;
        float v = A[((size_t)b * CD + c) * LL + l0 + l] * SA;
        _Float16 h = (_Float16)v;
        Ah[l * 104 + c] = h;
        Al[l * 104 + c] = (_Float16)(v - (float)h);
    }
    __syncthreads();
    if (LN) {
        int tl = tid >> 2, p = tid & 3;
        float s = 0.f, ss = 0.f;
        for (int j = 0; j < 24; j++) {
            int c = p * 24 + j;
            float v = ((float)Ah[tl * 104 + c] + (float)Al[tl * 104 + c]) * (1.f / SA);
            s += v; ss += v * v;
        }
        red1[tid] = s; red2[tid] = ss;
        __syncthreads();
        if (tid < 64) {
            float s4 = red1[tid * 4] + red1[tid * 4 + 1] + red1[tid * 4 + 2] + red1[tid * 4 + 3];
            float q4 = red2[tid * 4] + red2[tid * 4 + 1] + red2[tid * 4 + 2] + red2[tid * 4 + 3];
            float m = s4 / 96.f;
            sm[tid] = m;
            siv[tid] = rsqrtf(fmaxf(q4 / 96.f - m * m, 0.f) + 1e-5f);
        }
        __syncthreads();
    }
    int col = lane & 15, quad = lane >> 4;
    int n0 = w * 48;
    f32x4 zv4 = {0.f, 0.f, 0.f, 0.f};
    f32x4 acc[4][3];
    #pragma unroll
    for (int mi = 0; mi < 4; mi++)
        #pragma unroll
        for (int ni = 0; ni < 3; ni++) acc[mi][ni] = zv4;
    for (int c0 = 0; c0 < 96; c0 += 32) {
        f16x8 afh[4], afl[4], bfh[3], bfl[3];
        #pragma unroll
        for (int mi = 0; mi < 4; mi++) {
            int off = (16 * mi + col) * 104 + c0 + quad * 8;
            afh[mi] = *(const f16x8*)&Ah[off];
            afl[mi] = *(const f16x8*)&Al[off];
        }
        #pragma unroll
        for (int ni = 0; ni < 3; ni++) {
            size_t off = (size_t)(n0 + ni * 16 + col) * 96 + c0 + quad * 8;
            bfh[ni] = *(const f16x8*)&Wh[off];
            bfl[ni] = *(const f16x8*)&Wl[off];
        }
        #pragma unroll
        for (int mi = 0; mi < 4; mi++)
            #pragma unroll
            for (int ni = 0; ni < 3; ni++) {
                acc[mi][ni] = __builtin_amdgcn_mfma_f32_16x16x32_f16(afh[mi], bfl[ni], acc[mi][ni], 0, 0, 0);
                acc[mi][ni] = __builtin_amdgcn_mfma_f32_16x16x32_f16(afl[mi], bfh[ni], acc[mi][ni], 0, 0, 0);
                acc[mi][ni] = __builtin_amdgcn_mfma_f32_16x16x32_f16(afh[mi], bfh[ni], acc[mi][ni], 0, 0, 0);
            }
    }
    const float isc = 1.f / (SA * SW);
    #pragma unroll
    for (int ni = 0; ni < 3; ni++) {
        int d = n0 + ni * 16 + col;
        float wsv = LN ? wsum[d] : 0.f;
        float bvv = LN ? biasv[d] : 0.f;
        #pragma unroll
        for (int mi = 0; mi < 4; mi++)
            #pragma unroll
            for (int r = 0; r < 4; r++) {
                int tl = mi * 16 + quad * 4 + r;
                float v = acc[mi][ni][r] * isc;
                size_t t = (size_t)b * LL + l0 + tl;
                if (LN) {
                    v = (v - sm[tl] * wsv) * siv[tl] + bvv;
                    v = siluf(v) * SA;
                    _Float16 h = (_Float16)v;
                    outH[t * DD + d] = h;
                    outL[t * DD + d] = (_Float16)(v - (float)h);
                } else {
                    outF[t * DD + d] = v;
                }
            }
    }
}

// ---------------------------------------------------------------------------
// Depthwise causal conv (k=4) + bias + silu -> split f16 u planes (x SA).
__global__ __launch_bounds__(256) void conv_kernel(const float* __restrict__ xin,
        const float* __restrict__ cw, const float* __restrict__ cb,
        _Float16* __restrict__ uh, _Float16* __restrict__ ul)
{
    int gid = blockIdx.x * 256 + threadIdx.x;
    int dg = gid % (DD / 4);
    int tg = gid / (DD / 4);
    int b = tg / (LL / 4);
    int l0 = (tg % (LL / 4)) * 4;
    size_t rowbase = ((size_t)b * LL + l0) * DD + dg * 4;
    f32x4 r[7];
    #pragma unroll
    for (int j = 0; j < 7; j++) {
        int l = l0 - 3 + j;
        f32x4 z4 = {0.f, 0.f, 0.f, 0.f};
        r[j] = (l >= 0) ? *(const f32x4*)&xin[rowbase + (size_t)(j - 3) * DD] : z4;
    }
    float cwv[4][4], cb4[4];
    #pragma unroll
    for (int e = 0; e < 4; e++) {
        cb4[e] = cb[dg * 4 + e];
        #pragma unroll
        for (int j = 0; j < 4; j++) cwv[e][j] = cw[(dg * 4 + e) * 4 + j];
    }
    #pragma unroll
    for (int tt = 0; tt < 4; tt++) {
        f16x4 oh, ol;
        #pragma unroll
        for (int e = 0; e < 4; e++) {
            float s = cb4[e];
            #pragma unroll
            for (int j = 0; j < 4; j++) s = fmaf(cwv[e][j], r[tt + j][e], s);
            float u = siluf(s) * SA;
            _Float16 h = (_Float16)u;
            oh[e] = h;
            ol[e] = (_Float16)(u - (float)h);
        }
        *(f16x4*)&uh[rowbase + (size_t)tt * DD] = oh;
        *(f16x4*)&ul[rowbase + (size_t)tt * DD] = ol;
    }
}

// ---------------------------------------------------------------------------
// Token-major MFMA GEMM on f16x2 split planes.
template<int BR, int BC, int KD, int EPI>
__global__ __launch_bounds__(256) void mfma_gemm_tok(
    const _Float16* __restrict__ A0h, const _Float16* __restrict__ A0l,
    const _Float16* __restrict__ A1h, const _Float16* __restrict__ A1l,
    const _Float16* __restrict__ Wh, const _Float16* __restrict__ Wl,
    const float* __restrict__ bias, float oscale, float* __restrict__ outF,
    float* __restrict__ dtbp, float* __restrict__ Bbp, float* __restrict__ Cbp)
{
    int tid = threadIdx.x;
    int lane = tid & 63, w = tid >> 6;
    int mr = w % BR, nc = w / BR;
    int t0 = blockIdx.x * (BR * 64) + mr * 64;
    int n0 = nc * 48;
    int col = lane & 15, quad = lane >> 4;
    f32x4 zv4 = {0.f, 0.f, 0.f, 0.f};
    f32x4 acc[4][3];
    #pragma unroll
    for (int mi = 0; mi < 4; mi++)
        #pragma unroll
        for (int ni = 0; ni < 3; ni++) acc[mi][ni] = zv4;
    for (int k0 = 0; k0 < KD; k0 += 32) {
        const _Float16* Ah = (KD == 384 && k0 >= 192) ? A1h : A0h;
        const _Float16* Al = (KD == 384 && k0 >= 192) ? A1l : A0l;
        int kc = (KD == 384 && k0 >= 192) ? k0 - 192 : k0;
        f16x8 afh[4], afl[4], bfh[3], bfl[3];
        #pragma unroll
        for (int mi = 0; mi < 4; mi++) {
            size_t off = (size_t)(t0 + mi * 16 + col) * DD + kc + quad * 8;
            afh[mi] = *(const f16x8*)&Ah[off];
            afl[mi] = *(const f16x8*)&Al[off];
        }
        #pragma unroll
        for (int ni = 0; ni < 3; ni++) {
            size_t off = (size_t)(n0 + ni * 16 + col) * KD + k0 + quad * 8;
            bfh[ni] = *(const f16x8*)&Wh[off];
            bfl[ni] = *(const f16x8*)&Wl[off];
        }
        #pragma unroll
        for (int mi = 0; mi < 4; mi++)
            #pragma unroll
            for (int ni = 0; ni < 3; ni++) {
                acc[mi][ni] = __builtin_amdgcn_mfma_f32_16x16x32_f16(afh[mi], bfl[ni], acc[mi][ni], 0, 0, 0);
                acc[mi][ni] = __builtin_amdgcn_mfma_f32_16x16x32_f16(afl[mi], bfh[ni], acc[mi][ni], 0, 0, 0);
                acc[mi][ni] = __builtin_amdgcn_mfma_f32_16x16x32_f16(afh[mi], bfh[ni], acc[mi][ni], 0, 0, 0);
            }
    }
    if (EPI == 2) {
        int bq = t0 / LL;
        int lb = t0 % LL;
        #pragma unroll
        for (int ni = 0; ni < 3; ni++) {
            int d = n0 + ni * 16 + col;
            #pragma unroll
            for (int mi = 0; mi < 4; mi++) {
                f32x4 v;
                #pragma unroll
                for (int r = 0; r < 4; r++) v[r] = acc[mi][ni][r] * oscale;
                *(f32x4*)&outF[((size_t)(bq * 96 + d)) * LL + lb + mi * 16 + quad * 4] = v;
            }
        }
    } else if (EPI == 1) {
        #pragma unroll
        for (int ni = 0; ni < 3; ni++) {
            int d = n0 + ni * 16 + col;
            #pragma unroll
            for (int mi = 0; mi < 4; mi++)
                #pragma unroll
                for (int r = 0; r < 4; r++) {
                    size_t t = t0 + mi * 16 + quad * 4 + r;
                    float v = acc[mi][ni][r] * oscale;
                    if (d < 6)       dtbp[t * 8 + d] = v;
                    else if (d < 22) Bbp[t * 16 + (d - 6)] = v;
                    else if (d < 38) Cbp[t * 16 + (d - 22)] = v;
                    else if (d < 40) dtbp[t * 8 + (d - 32)] = 0.f;
                }
        }
    } else {
        #pragma unroll
        for (int ni = 0; ni < 3; ni++) {
            int d = n0 + ni * 16 + col;
            float bv = bias[d];
            #pragma unroll
            for (int mi = 0; mi < 4; mi++)
                #pragma unroll
                for (int r = 0; r < 4; r++) {
                    size_t t = t0 + mi * 16 + quad * 4 + r;
                    float v = acc[mi][ni][r] * oscale;
                    outF[t * DD + d] = siluf(v + bv);
                }
        }
    }
}

// ---------------------------------------------------------------------------
// Chunked selective scan. Pass 1 stores per-chunk sd (= sum of delta) and S.
__global__ __launch_bounds__(64) void scan_pass1(
    const _Float16* __restrict__ uh, const _Float16* __restrict__ ul,
    const float* __restrict__ dtb, const float* __restrict__ Bb,
    const float* __restrict__ A_log,
    const float* __restrict__ dtw, const float* __restrict__ dtbias,
    float* __restrict__ sd_ws, float* __restrict__ S_ws)
{
    int g = blockIdx.x, dblk = blockIdx.y, b = blockIdx.z;
    int d = dblk * 64 + threadIdx.x;
    size_t tbase = (size_t)b * LL + g * LC;
    float Av[NS];
    #pragma unroll
    for (int n = 0; n < NS; n++) Av[n] = -__expf(A_log[d * NS + n]);
    float w6[RR];
    #pragma unroll
    for (int r = 0; r < RR; r++) w6[r] = dtw[d * RR + r];
    float b2 = 2.f * dtbias[d];
    float h[NS];
    #pragma unroll
    for (int n = 0; n < NS; n++) h[n] = 0.f;
    float sd = 0.f;
    const _Float16* uhp = uh + tbase * DD + d;
    const _Float16* ulp = ul + tbase * DD + d;
    #pragma unroll 2
    for (int t = 0; t < LC; t++) {
        f32x4 d0 = *(const f32x4*)&dtb[(tbase + t) * 8];
        f32x4 d1 = *(const f32x4*)&dtb[(tbase + t) * 8 + 4];
        float s = b2;
        s = fmaf(d0[0], w6[0], s); s = fmaf(d0[1], w6[1], s);
        s = fmaf(d0[2], w6[2], s); s = fmaf(d0[3], w6[3], s);
        s = fmaf(d1[0], w6[4], s); s = fmaf(d1[1], w6[5], s);
        float dlt = softplusf(s);
        sd += dlt;
        float uu = ((float)uhp[(size_t)t * DD] + (float)ulp[(size_t)t * DD]) * (1.f / SA);
        float du = dlt * uu;
        f32x4 Bv[4];
        #pragma unroll
        for (int q = 0; q < 4; q++) Bv[q] = *(const f32x4*)&Bb[(tbase + t) * 16 + q * 4];
        #pragma unroll
        for (int n = 0; n < NS; n++) {
            float a = __expf(dlt * Av[n]);
            h[n] = fmaf(a, h[n], du * Bv[n >> 2][n & 3]);
        }
    }
    size_t o = ((size_t)(b * NG + g) * DD + d) * NS;
    sd_ws[(size_t)(b * NG + g) * DD + d] = sd;
    #pragma unroll
    for (int q = 0; q < 4; q++) {
        f32x4 sv;
        #pragma unroll
        for (int e = 0; e < 4; e++) sv[e] = h[q * 4 + e];
        *(f32x4*)(S_ws + o + q * 4) = sv;
    }
}

// ---------------------------------------------------------------------------
// 3-level parallel chunk-combine. Thread = (b, grp, d, n).
__global__ __launch_bounds__(256) void combine_a(
    const float* __restrict__ sd_ws, const float* __restrict__ S_ws,
    const float* __restrict__ A_log,
    float* __restrict__ Sg, float* __restrict__ sdg)
{
    int idx = blockIdx.x * 256 + threadIdx.x;       // [0, BZ*NGRP*DD*NS)
    int n = idx & 15;
    int d = (idx >> 4) % DD;
    int grp = (idx >> 4) / DD % NGRP;
    int b = idx / (NS * DD * NGRP);
    float Av = -__expf(A_log[d * NS + n]);
    float h = 0.f, sds = 0.f;
    #pragma unroll
    for (int j = 0; j < GSZ; j++) {
        int g = grp * GSZ + j;
        size_t cb = (size_t)(b * NG + g) * DD + d;
        float sd = sd_ws[cb];
        float a = __expf(sd * Av);
        h = fmaf(a, h, S_ws[cb * NS + n]);
        sds += sd;
    }
    size_t o = (size_t)(b * NGRP + grp) * DD + d;
    Sg[o * NS + n] = h;
    if (n == 0) sdg[o] = sds;
}

__global__ __launch_bounds__(256) void combine_b(
    const float* __restrict__ Sg, const float* __restrict__ sdg,
    const float* __restrict__ A_log, float* __restrict__ Hgrp)
{
    int idx = blockIdx.x * 256 + threadIdx.x;       // [0, BZ*DD*NS)
    int n = idx & 15;
    int d = (idx >> 4) % DD;
    int b = idx / (NS * DD);
    float Av = -__expf(A_log[d * NS + n]);
    float h = 0.f;
    #pragma unroll
    for (int grp = 0; grp < NGRP; grp++) {
        size_t o = (size_t)(b * NGRP + grp) * DD + d;
        Hgrp[o * NS + n] = h;
        float a = __expf(sdg[o] * Av);
        h = fmaf(a, h, Sg[o * NS + n]);
    }
}

__global__ __launch_bounds__(256) void combine_c(
    const float* __restrict__ sd_ws, const float* __restrict__ S_ws,
    const float* __restrict__ Hgrp, const float* __restrict__ A_log,
    float* __restrict__ H_ws)
{
    int idx = blockIdx.x * 256 + threadIdx.x;       // [0, BZ*NGRP*DD*NS)
    int n = idx & 15;
    int d = (idx >> 4) % DD;
    int grp = (idx >> 4) / DD % NGRP;
    int b = idx / (NS * DD * NGRP);
    float Av = -__expf(A_log[d * NS + n]);
    float h = Hgrp[((size_t)(b * NGRP + grp) * DD + d) * NS + n];
    #pragma unroll
    for (int j = 0; j < GSZ; j++) {
        int g = grp * GSZ + j;
        size_t cb = (size_t)(b * NG + g) * DD + d;
        H_ws[cb * NS + n] = h;
        float a = __expf(sd_ws[cb] * Av);
        h = fmaf(a, h, S_ws[cb * NS + n]);
    }
}

// ---------------------------------------------------------------------------
__global__ __launch_bounds__(64) void scan_pass2(
    const _Float16* __restrict__ uh, const _Float16* __restrict__ ul,
    const float* __restrict__ dtb, const float* __restrict__ Bb,
    const float* __restrict__ Cb, const float* __restrict__ A_log,
    const float* __restrict__ dtw, const float* __restrict__ dtbias,
    const float* __restrict__ H_ws, const float* __restrict__ zs,
    const float* __restrict__ Dvec,
    _Float16* __restrict__ yh, _Float16* __restrict__ yl)
{
    int g = blockIdx.x, dblk = blockIdx.y, b = blockIdx.z;
    int d = dblk * 64 + threadIdx.x;
    size_t tbase = (size_t)b * LL + g * LC;
    float Av[NS];
    #pragma unroll
    for (int n = 0; n < NS; n++) Av[n] = -__expf(A_log[d * NS + n]);
    float w6[RR];
    #pragma unroll
    for (int r = 0; r < RR; r++) w6[r] = dtw[d * RR + r];
    float b2 = 2.f * dtbias[d];
    float h[NS];
    size_t o = ((size_t)(b * NG + g) * DD + d) * NS;
    #pragma unroll
    for (int q = 0; q < 4; q++) {
        f32x4 hv = *(const f32x4*)(H_ws + o + q * 4);
        #pragma unroll
        for (int e = 0; e < 4; e++) h[q * 4 + e] = hv[e];
    }
    float Dv = Dvec[d];
    const _Float16* uhp = uh + tbase * DD + d;
    const _Float16* ulp = ul + tbase * DD + d;
    const float* zp = zs + tbase * DD + d;
    _Float16* yhp = yh + tbase * DD + d;
    _Float16* ylp = yl + tbase * DD + d;
    #pragma unroll 2
    for (int t = 0; t < LC; t++) {
        f32x4 d0 = *(const f32x4*)&dtb[(tbase + t) * 8];
        f32x4 d1 = *(const f32x4*)&dtb[(tbase + t) * 8 + 4];
        float s = b2;
        s = fmaf(d0[0], w6[0], s); s = fmaf(d0[1], w6[1], s);
        s = fmaf(d0[2], w6[2], s); s = fmaf(d0[3], w6[3], s);
        s = fmaf(d1[0], w6[4], s); s = fmaf(d1[1], w6[5], s);
        float dlt = softplusf(s);
        float uu = ((float)uhp[(size_t)t * DD] + (float)ulp[(size_t)t * DD]) * (1.f / SA);
        float du = dlt * uu;
        f32x4 Bv[4], Cv[4];
        #pragma unroll
        for (int q = 0; q < 4; q++) {
            Bv[q] = *(const f32x4*)&Bb[(tbase + t) * 16 + q * 4];
            Cv[q] = *(const f32x4*)&Cb[(tbase + t) * 16 + q * 4];
        }
        float yv = 0.f;
        #pragma unroll
        for (int n = 0; n < NS; n++) {
            float a = __expf(dlt * Av[n]);
            h[n] = fmaf(a, h[n], du * Bv[n >> 2][n & 3]);
            yv = fmaf(h[n], Cv[n >> 2][n & 3], yv);
        }
        float zv = zp[(size_t)t * DD];
        float y = (yv + uu * Dv) * zv * SY;
        _Float16 hh = (_Float16)y;
        yhp[(size_t)t * DD] = hh;
        ylp[(size_t)t * DD] = (_Float16)(y - (float)hh);
    }
}

// ---------------------------------------------------------------------------
extern "C" void kernel_launch(void* const* d_in, const int* in_sizes, int n_in,
                              void* d_out, int out_size, void* d_ws, size_t ws_size,
                              hipStream_t stream)
{
    (void)in_sizes; (void)n_in; (void)out_size; (void)ws_size;
    const float* x        = (const float*)d_in[0];
    const float* K        = (const float*)d_in[1];
    const float* Q        = (const float*)d_in[2];
    const float* in_projw = (const float*)d_in[3];
    const float* conv_w   = (const float*)d_in[4];
    const float* conv_b   = (const float*)d_in[5];
    const float* k_ln_g   = (const float*)d_in[6];
    const float* k_ln_b   = (const float*)d_in[7];
    const float* k_w      = (const float*)d_in[8];
    const float* k_b      = (const float*)d_in[9];
    const float* q_ln_g   = (const float*)d_in[10];
    const float* q_ln_b   = (const float*)d_in[11];
    const float* q_w      = (const float*)d_in[12];
    const float* q_b      = (const float*)d_in[13];
    const float* dtbc_w   = (const float*)d_in[14];
    const float* dt_w     = (const float*)d_in[15];
    const float* dt_b     = (const float*)d_in[16];
    const float* gate_w   = (const float*)d_in[17];
    const float* gate_b   = (const float*)d_in[18];
    const float* A_log    = (const float*)d_in[19];
    const float* Dvec     = (const float*)d_in[20];
    const float* out_w    = (const float*)d_in[21];
    float* out = (float*)d_out;

    const size_t S0 = (size_t)MTOK * DD;
    char* base = (char*)d_ws;
    size_t off = 0;
    auto alloc = [&](size_t bytes) {
        char* p = base + off;
        off += (bytes + 255) & ~(size_t)255;
        return p;
    };
    float*     xin   = (float*)alloc(S0 * 4);            // reused as zs
    _Float16*  uH    = (_Float16*)alloc(S0 * 2);
    _Float16*  uL    = (_Float16*)alloc(S0 * 2);
    _Float16*  KpH   = (_Float16*)alloc(S0 * 2);         // reused as yH
    _Float16*  KpL   = (_Float16*)alloc(S0 * 2);         // reused as yL
    _Float16*  QpH   = (_Float16*)alloc(S0 * 2);
    _Float16*  QpL   = (_Float16*)alloc(S0 * 2);
    float*     dtbB  = (float*)alloc((size_t)MTOK * 8 * 4);
    float*     Bb    = (float*)alloc((size_t)MTOK * 16 * 4);
    float*     Cb    = (float*)alloc((size_t)MTOK * 16 * 4);
    float*     gwK   = (float*)alloc(DD * CD * 4);
    float*     gwQ   = (float*)alloc(DD * CD * 4);
    float*     wsumK = (float*)alloc(DD * 4);
    float*     biasK = (float*)alloc(DD * 4);
    float*     wsumQ = (float*)alloc(DD * 4);
    float*     biasQ = (float*)alloc(DD * 4);
    _Float16*  ipWh  = (_Float16*)alloc(DD * CD * 2);
    _Float16*  ipWl  = (_Float16*)alloc(DD * CD * 2);
    _Float16*  kWh   = (_Float16*)alloc(DD * CD * 2);
    _Float16*  kWl   = (_Float16*)alloc(DD * CD * 2);
    _Float16*  qWh   = (_Float16*)alloc(DD * CD * 2);
    _Float16*  qWl   = (_Float16*)alloc(DD * CD * 2);
    _Float16*  dbWh  = (_Float16*)alloc(48 * 384 * 2);
    _Float16*  dbWl  = (_Float16*)alloc(48 * 384 * 2);
    _Float16*  gWh   = (_Float16*)alloc(DD * 384 * 2);
    _Float16*  gWl   = (_Float16*)alloc(DD * 384 * 2);
    _Float16*  oWh   = (_Float16*)alloc(96 * DD * 2);
    _Float16*  oWl   = (_Float16*)alloc(96 * DD * 2);
    float*     sd_ws = (float*)alloc((size_t)BZ * NG * DD * 4);
    float*     S_ws  = (float*)alloc((size_t)BZ * NG * DD * NS * 4);
    float*     H_ws  = (float*)alloc((size_t)BZ * NG * DD * NS * 4);
    float*     Sg    = (float*)alloc((size_t)BZ * NGRP * DD * NS * 4);
    float*     sdg   = (float*)alloc((size_t)BZ * NGRP * DD * 4);
    float*     Hgrp  = (float*)alloc((size_t)BZ * NGRP * DD * NS * 4);
    float*    zs = xin;
    _Float16* yH = KpH;
    _Float16* yL = KpL;

    prep_kernel<<<dim3(DD, 2), 96, 0, stream>>>(k_ln_g, k_ln_b, k_w, k_b,
        q_ln_g, q_ln_b, q_w, q_b, gwK, wsumK, biasK, gwQ, wsumQ, biasQ);
    {
        const int total = 18432 * 5 + 73728;
        split_all_kernel<<<(total + 255) / 256, 256, 0, stream>>>(
            in_projw, gwK, gwQ, dtbc_w, gate_w, out_w,
            ipWh, ipWl, kWh, kWl, qWh, qWl, dbWh, dbWl, gWh, gWl, oWh, oWl);
    }

    mfma_projCH<false><<<dim3(LL / 64, BZ), 256, 0, stream>>>(
        x, ipWh, ipWl, nullptr, nullptr, xin, nullptr, nullptr);
    mfma_projCH<true><<<dim3(LL / 64, BZ), 256, 0, stream>>>(
        K, kWh, kWl, wsumK, biasK, nullptr, KpH, KpL);
    mfma_projCH<true><<<dim3(LL / 64, BZ), 256, 0, stream>>>(
        Q, qWh, qWl, wsumQ, biasQ, nullptr, QpH, QpL);
    conv_kernel<<<(MTOK / 4) * (DD / 4) / 256, 256, 0, stream>>>(xin, conv_w, conv_b, uH, uL);
    mfma_gemm_tok<4, 1, 384, 1><<<MTOK / 256, 256, 0, stream>>>(
        uH, uL, KpH, KpL, dbWh, dbWl, nullptr, 1.f / (SA * SW), nullptr, dtbB, Bb, Cb);
    mfma_gemm_tok<1, 4, 384, 0><<<MTOK / 64, 256, 0, stream>>>(
        uH, uL, QpH, QpL, gWh, gWl, gate_b, 1.f / (SA * SW), zs, nullptr, nullptr, nullptr);
    scan_pass1<<<dim3(NG, DD / 64, BZ), 64, 0, stream>>>(
        uH, uL, dtbB, Bb, A_log, dt_w, dt_b, sd_ws, S_ws);
    combine_a<<<(BZ * NGRP * DD * NS) / 256, 256, 0, stream>>>(sd_ws, S_ws, A_log, Sg, sdg);
    combine_b<<<(BZ * DD * NS) / 256, 256, 0, stream>>>(Sg, sdg, A_log, Hgrp);
    combine_c<<<(BZ * NGRP * DD * NS) / 256, 256, 0, stream>>>(sd_ws, S_ws, Hgrp, A_log, H_ws);
    scan_pass2<<<dim3(NG, DD / 64, BZ), 64, 0, stream>>>(
        uH, uL, dtbB, Bb, Cb, A_log, dt_w, dt_b, H_ws, zs, Dvec, yH, yL);
    mfma_gemm_tok<2, 2, 192, 2><<<MTOK / 128, 256, 0, stream>>>(
        yH, yL, nullptr, nullptr, oWh, oWl, nullptr, 1.f / (SY * SW), out, nullptr, nullptr, nullptr);
}

// Round 5
// 415.958 us; speedup vs baseline: 1.2270x; 1.0225x over previous
//
#include <hip/hip_runtime.h>
#include <cstdint>
#include <cstddef>

#define BZ 4
#define CD 96
#define LL 9216
#define DD 192
#define NS 16
#define RR 6
#define LC 32
#define NG 288
#define NGRP 16
#define GSZ 18
#define MTOK (BZ * LL)

#define SA 256.0f
#define SW 1024.0f
#define SY 16.0f

typedef _Float16 f16x8 __attribute__((ext_vector_type(8)));
typedef _Float16 f16x4 __attribute__((ext_vector_type(4)));
typedef float f32x4 __attribute__((ext_vector_type(4)));

__device__ __forceinline__ float siluf(float x) {
    return x / (1.f + __expf(-x));
}
__device__ __forceinline__ float softplusf(float x) {
    return fmaxf(x, 0.f) + log1pf(__expf(-fabsf(x)));
}

// ---------------------------------------------------------------------------
__global__ void prep_kernel(const float* kg, const float* kb, const float* kw, const float* kbias,
                            const float* qg, const float* qb, const float* qw, const float* qbias,
                            float* gwK, float* wsumK, float* biasK,
                            float* gwQ, float* wsumQ, float* biasQ) {
    int d = blockIdx.x;
    const float* g  = blockIdx.y ? qg : kg;
    const float* lb = blockIdx.y ? qb : kb;
    const float* w  = blockIdx.y ? qw : kw;
    const float* b2 = blockIdx.y ? qbias : kbias;
    float* gw = blockIdx.y ? gwQ : gwK;
    float* wsv = blockIdx.y ? wsumQ : wsumK;
    float* bv = blockIdx.y ? biasQ : biasK;
    int c = threadIdx.x;
    __shared__ float s1[96], s2[96];
    float wv = w[d * 96 + c];
    float gv = g[c] * wv;
    gw[d * 96 + c] = gv;
    s1[c] = gv;
    s2[c] = lb[c] * wv;
    __syncthreads();
    if (c < 32) { s1[c] += s1[c + 64]; s2[c] += s2[c + 64]; }
    __syncthreads();
    for (int s = 32; s >= 1; s >>= 1) {
        if (c < s) { s1[c] += s1[c + s]; s2[c] += s2[c + s]; }
        __syncthreads();
    }
    if (c == 0) { wsv[d] = s1[0]; bv[d] = b2[d] + s2[0]; }
}

// ---------------------------------------------------------------------------
__global__ __launch_bounds__(256) void split_all_kernel(
    const float* __restrict__ s0, const float* __restrict__ s1, const float* __restrict__ s2,
    const float* __restrict__ s3, const float* __restrict__ s4, const float* __restrict__ s5,
    _Float16* __restrict__ d0h, _Float16* __restrict__ d0l,
    _Float16* __restrict__ d1h, _Float16* __restrict__ d1l,
    _Float16* __restrict__ d2h, _Float16* __restrict__ d2l,
    _Float16* __restrict__ d3h, _Float16* __restrict__ d3l,
    _Float16* __restrict__ d4h, _Float16* __restrict__ d4l,
    _Float16* __restrict__ d5h, _Float16* __restrict__ d5l)
{
    int idx = blockIdx.x * 256 + threadIdx.x;
    const int C0 = 18432, C1 = 18432, C2 = 18432, C3 = 18432, C4 = 73728, C5 = 18432;
    const float* src; _Float16* dh; _Float16* dl; int i; bool pad = false;
    if (idx < C0) { src = s0; dh = d0h; dl = d0l; i = idx; }
    else if (idx < C0 + C1) { src = s1; dh = d1h; dl = d1l; i = idx - C0; }
    else if (idx < C0 + C1 + C2) { src = s2; dh = d2h; dl = d2l; i = idx - C0 - C1; }
    else if (idx < C0 + C1 + C2 + C3) {
        src = s3; dh = d3h; dl = d3l; i = idx - C0 - C1 - C2;
        pad = (i / 384) >= 38;   // dtbc_w: 38 real rows padded to 48
    }
    else if (idx < C0 + C1 + C2 + C3 + C4) { src = s4; dh = d4h; dl = d4l; i = idx - C0 - C1 - C2 - C3; }
    else if (idx < C0 + C1 + C2 + C3 + C4 + C5) { src = s5; dh = d5h; dl = d5l; i = idx - C0 - C1 - C2 - C3 - C4; }
    else return;
    float v = pad ? 0.f : src[i] * SW;
    _Float16 h = (_Float16)v;
    dh[i] = h;
    dl[i] = (_Float16)(v - (float)h);
}

// ---------------------------------------------------------------------------
// Merged MFMA projection (x / K / Q selected by blockIdx.z), K=96, N=192.
__global__ __launch_bounds__(256) void mfma_projCH3(
    const float* __restrict__ xA, const float* __restrict__ KA, const float* __restrict__ QA,
    const _Float16* __restrict__ ipWh, const _Float16* __restrict__ ipWl,
    const _Float16* __restrict__ kWh, const _Float16* __restrict__ kWl,
    const _Float16* __restrict__ qWh, const _Float16* __restrict__ qWl,
    const float* __restrict__ wsumK, const float* __restrict__ biasK,
    const float* __restrict__ wsumQ, const float* __restrict__ biasQ,
    float* __restrict__ xin,
    _Float16* __restrict__ KpH, _Float16* __restrict__ KpL,
    _Float16* __restrict__ QpH, _Float16* __restrict__ QpL)
{
    int which = blockIdx.z;
    const float* A = which == 0 ? xA : (which == 1 ? KA : QA);
    const _Float16* Wh = which == 0 ? ipWh : (which == 1 ? kWh : qWh);
    const _Float16* Wl = which == 0 ? ipWl : (which == 1 ? kWl : qWl);
    const float* wsum = which == 1 ? wsumK : wsumQ;
    const float* biasv = which == 1 ? biasK : biasQ;
    _Float16* outH = which == 1 ? KpH : QpH;
    _Float16* outL = which == 1 ? KpL : QpL;
    bool LN = which != 0;

    int b = blockIdx.y;
    int l0 = blockIdx.x * 64;
    int tid = threadIdx.x;
    int lane = tid & 63, w = tid >> 6;
    __shared__ __align__(16) _Float16 Ah[64 * 104];
    __shared__ __align__(16) _Float16 Al[64 * 104];
    __shared__ float sm[64], siv[64];
    __shared__ float red1[256], red2[256];
    for (int i = tid; i < 96 * 64; i += 256) {
        int c = i >> 6, l = i & 63;
        float v = A[((size_t)b * CD + c) * LL + l0 + l] * SA;
        _Float16 h = (_Float16)v;
        Ah[l * 104 + c] = h;
        Al[l * 104 + c] = (_Float16)(v - (float)h);
    }
    __syncthreads();
    if (LN) {
        int tl = tid >> 2, p = tid & 3;
        float s = 0.f, ss = 0.f;
        for (int j = 0; j < 24; j++) {
            int c = p * 24 + j;
            float v = ((float)Ah[tl * 104 + c] + (float)Al[tl * 104 + c]) * (1.f / SA);
            s += v; ss += v * v;
        }
        red1[tid] = s; red2[tid] = ss;
        __syncthreads();
        if (tid < 64) {
            float s4 = red1[tid * 4] + red1[tid * 4 + 1] + red1[tid * 4 + 2] + red1[tid * 4 + 3];
            float q4 = red2[tid * 4] + red2[tid * 4 + 1] + red2[tid * 4 + 2] + red2[tid * 4 + 3];
            float m = s4 / 96.f;
            sm[tid] = m;
            siv[tid] = rsqrtf(fmaxf(q4 / 96.f - m * m, 0.f) + 1e-5f);
        }
        __syncthreads();
    }
    int col = lane & 15, quad = lane >> 4;
    int n0 = w * 48;
    f32x4 zv4 = {0.f, 0.f, 0.f, 0.f};
    f32x4 acc[4][3];
    #pragma unroll
    for (int mi = 0; mi < 4; mi++)
        #pragma unroll
        for (int ni = 0; ni < 3; ni++) acc[mi][ni] = zv4;
    for (int c0 = 0; c0 < 96; c0 += 32) {
        f16x8 afh[4], afl[4], bfh[3], bfl[3];
        #pragma unroll
        for (int mi = 0; mi < 4; mi++) {
            int off = (16 * mi + col) * 104 + c0 + quad * 8;
            afh[mi] = *(const f16x8*)&Ah[off];
            afl[mi] = *(const f16x8*)&Al[off];
        }
        #pragma unroll
        for (int ni = 0; ni < 3; ni++) {
            size_t off = (size_t)(n0 + ni * 16 + col) * 96 + c0 + quad * 8;
            bfh[ni] = *(const f16x8*)&Wh[off];
            bfl[ni] = *(const f16x8*)&Wl[off];
        }
        #pragma unroll
        for (int mi = 0; mi < 4; mi++)
            #pragma unroll
            for (int ni = 0; ni < 3; ni++) {
                acc[mi][ni] = __builtin_amdgcn_mfma_f32_16x16x32_f16(afh[mi], bfl[ni], acc[mi][ni], 0, 0, 0);
                acc[mi][ni] = __builtin_amdgcn_mfma_f32_16x16x32_f16(afl[mi], bfh[ni], acc[mi][ni], 0, 0, 0);
                acc[mi][ni] = __builtin_amdgcn_mfma_f32_16x16x32_f16(afh[mi], bfh[ni], acc[mi][ni], 0, 0, 0);
            }
    }
    const float isc = 1.f / (SA * SW);
    #pragma unroll
    for (int ni = 0; ni < 3; ni++) {
        int d = n0 + ni * 16 + col;
        float wsv = LN ? wsum[d] : 0.f;
        float bvv = LN ? biasv[d] : 0.f;
        #pragma unroll
        for (int mi = 0; mi < 4; mi++)
            #pragma unroll
            for (int r = 0; r < 4; r++) {
                int tl = mi * 16 + quad * 4 + r;
                float v = acc[mi][ni][r] * isc;
                size_t t = (size_t)b * LL + l0 + tl;
                if (LN) {
                    v = (v - sm[tl] * wsv) * siv[tl] + bvv;
                    v = siluf(v) * SA;
                    _Float16 h = (_Float16)v;
                    outH[t * DD + d] = h;
                    outL[t * DD + d] = (_Float16)(v - (float)h);
                } else {
                    xin[t * DD + d] = v;
                }
            }
    }
}

// ---------------------------------------------------------------------------
__global__ __launch_bounds__(256) void conv_kernel(const float* __restrict__ xin,
        const float* __restrict__ cw, const float* __restrict__ cb,
        _Float16* __restrict__ uh, _Float16* __restrict__ ul)
{
    int gid = blockIdx.x * 256 + threadIdx.x;
    int dg = gid % (DD / 4);
    int tg = gid / (DD / 4);
    int b = tg / (LL / 4);
    int l0 = (tg % (LL / 4)) * 4;
    size_t rowbase = ((size_t)b * LL + l0) * DD + dg * 4;
    f32x4 r[7];
    #pragma unroll
    for (int j = 0; j < 7; j++) {
        int l = l0 - 3 + j;
        f32x4 z4 = {0.f, 0.f, 0.f, 0.f};
        r[j] = (l >= 0) ? *(const f32x4*)&xin[rowbase + (size_t)(j - 3) * DD] : z4;
    }
    float cwv[4][4], cb4[4];
    #pragma unroll
    for (int e = 0; e < 4; e++) {
        cb4[e] = cb[dg * 4 + e];
        #pragma unroll
        for (int j = 0; j < 4; j++) cwv[e][j] = cw[(dg * 4 + e) * 4 + j];
    }
    #pragma unroll
    for (int tt = 0; tt < 4; tt++) {
        f16x4 oh, ol;
        #pragma unroll
        for (int e = 0; e < 4; e++) {
            float s = cb4[e];
            #pragma unroll
            for (int j = 0; j < 4; j++) s = fmaf(cwv[e][j], r[tt + j][e], s);
            float u = siluf(s) * SA;
            _Float16 h = (_Float16)u;
            oh[e] = h;
            ol[e] = (_Float16)(u - (float)h);
        }
        *(f16x4*)&uh[rowbase + (size_t)tt * DD] = oh;
        *(f16x4*)&ul[rowbase + (size_t)tt * DD] = ol;
    }
}

// ---------------------------------------------------------------------------
// Pipelined 32tok x 48n wave-tile GEMM core (split f16x2, 3-MFMA accumulate).
__device__ __forceinline__ void mfma_set3(
    const f16x8 (&ah)[2], const f16x8 (&al)[2],
    const f16x8 (&bh)[3], const f16x8 (&bl)[3], f32x4 (&acc)[2][3])
{
    #pragma unroll
    for (int mi = 0; mi < 2; mi++)
        #pragma unroll
        for (int ni = 0; ni < 3; ni++) {
            acc[mi][ni] = __builtin_amdgcn_mfma_f32_16x16x32_f16(ah[mi], bl[ni], acc[mi][ni], 0, 0, 0);
            acc[mi][ni] = __builtin_amdgcn_mfma_f32_16x16x32_f16(al[mi], bh[ni], acc[mi][ni], 0, 0, 0);
            acc[mi][ni] = __builtin_amdgcn_mfma_f32_16x16x32_f16(ah[mi], bh[ni], acc[mi][ni], 0, 0, 0);
        }
}

template<int KD>
__device__ __forceinline__ void gemm_core32(
    const _Float16* __restrict__ A0h, const _Float16* __restrict__ A0l,
    const _Float16* __restrict__ A1h, const _Float16* __restrict__ A1l,
    const _Float16* __restrict__ Wh, const _Float16* __restrict__ Wl,
    int t0, int n0, int col, int quad, f32x4 (&acc)[2][3])
{
    auto loadA = [&](int k0, f16x8 (&ah)[2], f16x8 (&al)[2]) {
        const _Float16* Ah = (KD == 384 && k0 >= 192) ? A1h : A0h;
        const _Float16* Al = (KD == 384 && k0 >= 192) ? A1l : A0l;
        int kc = (KD == 384 && k0 >= 192) ? k0 - 192 : k0;
        #pragma unroll
        for (int mi = 0; mi < 2; mi++) {
            size_t off = (size_t)(t0 + mi * 16 + col) * DD + kc + quad * 8;
            ah[mi] = *(const f16x8*)&Ah[off];
            al[mi] = *(const f16x8*)&Al[off];
        }
    };
    auto loadB = [&](int k0, f16x8 (&bh)[3], f16x8 (&bl)[3]) {
        #pragma unroll
        for (int ni = 0; ni < 3; ni++) {
            size_t off = (size_t)(n0 + ni * 16 + col) * KD + k0 + quad * 8;
            bh[ni] = *(const f16x8*)&Wh[off];
            bl[ni] = *(const f16x8*)&Wl[off];
        }
    };
    f16x8 a0h[2], a0l[2], b0h[3], b0l[3];
    f16x8 a1h[2], a1l[2], b1h[3], b1l[3];
    loadA(0, a0h, a0l);
    loadB(0, b0h, b0l);
    #pragma unroll
    for (int k0 = 0; k0 < KD; k0 += 64) {
        if (k0 + 32 < KD) { loadA(k0 + 32, a1h, a1l); loadB(k0 + 32, b1h, b1l); }
        mfma_set3(a0h, a0l, b0h, b0l, acc);
        if (k0 + 64 < KD) { loadA(k0 + 64, a0h, a0l); loadB(k0 + 64, b0h, b0l); }
        if (k0 + 32 < KD) mfma_set3(a1h, a1l, b1h, b1l, acc);
    }
}

// ---------------------------------------------------------------------------
// Fused z-GEMM + xdbl-GEMM (K=384). blockIdx.x < 1152 -> z path, else xdbl.
__global__ __launch_bounds__(256, 3) void gemm_zx(
    const _Float16* __restrict__ uH, const _Float16* __restrict__ uL,
    const _Float16* __restrict__ QpH, const _Float16* __restrict__ QpL,
    const _Float16* __restrict__ KpH, const _Float16* __restrict__ KpL,
    const _Float16* __restrict__ gWh, const _Float16* __restrict__ gWl,
    const _Float16* __restrict__ dbWh, const _Float16* __restrict__ dbWl,
    const float* __restrict__ gate_b,
    float* __restrict__ zs, float* __restrict__ dtbp,
    float* __restrict__ Bbp, float* __restrict__ Cbp)
{
    int tid = threadIdx.x;
    int lane = tid & 63, w = tid >> 6;
    int col = lane & 15, quad = lane >> 4;
    const int ZB = (MTOK / 64) * 2;   // 1152
    bool isz = (int)blockIdx.x < ZB;
    int t0, n0;
    const _Float16 *A1h, *A1l, *Bh, *Bl;
    if (isz) {
        int bx = blockIdx.x;
        t0 = (bx >> 1) * 64 + (w & 1) * 32;
        n0 = (bx & 1) * 96 + (w >> 1) * 48;
        A1h = QpH; A1l = QpL; Bh = gWh; Bl = gWl;
    } else {
        int bx = blockIdx.x - ZB;
        t0 = bx * 128 + w * 32;
        n0 = 0;
        A1h = KpH; A1l = KpL; Bh = dbWh; Bl = dbWl;
    }
    f32x4 zv4 = {0.f, 0.f, 0.f, 0.f};
    f32x4 acc[2][3];
    #pragma unroll
    for (int mi = 0; mi < 2; mi++)
        #pragma unroll
        for (int ni = 0; ni < 3; ni++) acc[mi][ni] = zv4;
    gemm_core32<384>(uH, uL, A1h, A1l, Bh, Bl, t0, n0, col, quad, acc);
    const float osc = 1.f / (SA * SW);
    if (isz) {
        #pragma unroll
        for (int ni = 0; ni < 3; ni++) {
            int d = n0 + ni * 16 + col;
            float bv = gate_b[d];
            #pragma unroll
            for (int mi = 0; mi < 2; mi++)
                #pragma unroll
                for (int r = 0; r < 4; r++) {
                    size_t t = t0 + mi * 16 + quad * 4 + r;
                    zs[t * DD + d] = siluf(acc[mi][ni][r] * osc + bv);
                }
        }
    } else {
        #pragma unroll
        for (int ni = 0; ni < 3; ni++) {
            int d = n0 + ni * 16 + col;
            #pragma unroll
            for (int mi = 0; mi < 2; mi++)
                #pragma unroll
                for (int r = 0; r < 4; r++) {
                    size_t t = t0 + mi * 16 + quad * 4 + r;
                    float v = acc[mi][ni][r] * osc;
                    if (d < 6)       dtbp[t * 8 + d] = v;
                    else if (d < 22) Bbp[t * 16 + (d - 6)] = v;
                    else if (d < 38) Cbp[t * 16 + (d - 22)] = v;
                    else if (d < 40) dtbp[t * 8 + (d - 32)] = 0.f;
                }
        }
    }
}

// ---------------------------------------------------------------------------
// Final out-projection (K=192), transposed fp32 store into (B,96,L).
__global__ __launch_bounds__(256, 3) void gemm_out(
    const _Float16* __restrict__ yH, const _Float16* __restrict__ yL,
    const _Float16* __restrict__ oWh, const _Float16* __restrict__ oWl,
    float* __restrict__ outF)
{
    int tid = threadIdx.x;
    int lane = tid & 63, w = tid >> 6;
    int col = lane & 15, quad = lane >> 4;
    int t0 = blockIdx.x * 64 + (w & 1) * 32;
    int n0 = (w >> 1) * 48;
    f32x4 zv4 = {0.f, 0.f, 0.f, 0.f};
    f32x4 acc[2][3];
    #pragma unroll
    for (int mi = 0; mi < 2; mi++)
        #pragma unroll
        for (int ni = 0; ni < 3; ni++) acc[mi][ni] = zv4;
    gemm_core32<192>(yH, yL, nullptr, nullptr, oWh, oWl, t0, n0, col, quad, acc);
    const float osc = 1.f / (SY * SW);
    int bq = t0 / LL;
    int lb = t0 % LL;
    #pragma unroll
    for (int ni = 0; ni < 3; ni++) {
        int d = n0 + ni * 16 + col;
        #pragma unroll
        for (int mi = 0; mi < 2; mi++) {
            f32x4 v;
            #pragma unroll
            for (int r = 0; r < 4; r++) v[r] = acc[mi][ni][r] * osc;
            *(f32x4*)&outF[((size_t)(bq * 96 + d)) * LL + lb + mi * 16 + quad * 4] = v;
        }
    }
}

// ---------------------------------------------------------------------------
// Chunked selective scan. Pass 1 stores per-chunk sd (= sum of delta) and S.
__global__ __launch_bounds__(64) void scan_pass1(
    const _Float16* __restrict__ uh, const _Float16* __restrict__ ul,
    const float* __restrict__ dtb, const float* __restrict__ Bb,
    const float* __restrict__ A_log,
    const float* __restrict__ dtw, const float* __restrict__ dtbias,
    float* __restrict__ sd_ws, float* __restrict__ S_ws)
{
    int g = blockIdx.x, dblk = blockIdx.y, b = blockIdx.z;
    int d = dblk * 64 + threadIdx.x;
    size_t tbase = (size_t)b * LL + g * LC;
    float Av[NS];
    #pragma unroll
    for (int n = 0; n < NS; n++) Av[n] = -__expf(A_log[d * NS + n]);
    float w6[RR];
    #pragma unroll
    for (int r = 0; r < RR; r++) w6[r] = dtw[d * RR + r];
    float b2 = 2.f * dtbias[d];
    float h[NS];
    #pragma unroll
    for (int n = 0; n < NS; n++) h[n] = 0.f;
    float sd = 0.f;
    const _Float16* uhp = uh + tbase * DD + d;
    const _Float16* ulp = ul + tbase * DD + d;
    #pragma unroll 2
    for (int t = 0; t < LC; t++) {
        f32x4 d0 = *(const f32x4*)&dtb[(tbase + t) * 8];
        f32x4 d1 = *(const f32x4*)&dtb[(tbase + t) * 8 + 4];
        float s = b2;
        s = fmaf(d0[0], w6[0], s); s = fmaf(d0[1], w6[1], s);
        s = fmaf(d0[2], w6[2], s); s = fmaf(d0[3], w6[3], s);
        s = fmaf(d1[0], w6[4], s); s = fmaf(d1[1], w6[5], s);
        float dlt = softplusf(s);
        sd += dlt;
        float uu = ((float)uhp[(size_t)t * DD] + (float)ulp[(size_t)t * DD]) * (1.f / SA);
        float du = dlt * uu;
        f32x4 Bv[4];
        #pragma unroll
        for (int q = 0; q < 4; q++) Bv[q] = *(const f32x4*)&Bb[(tbase + t) * 16 + q * 4];
        #pragma unroll
        for (int n = 0; n < NS; n++) {
            float a = __expf(dlt * Av[n]);
            h[n] = fmaf(a, h[n], du * Bv[n >> 2][n & 3]);
        }
    }
    size_t o = ((size_t)(b * NG + g) * DD + d) * NS;
    sd_ws[(size_t)(b * NG + g) * DD + d] = sd;
    #pragma unroll
    for (int q = 0; q < 4; q++) {
        f32x4 sv;
        #pragma unroll
        for (int e = 0; e < 4; e++) sv[e] = h[q * 4 + e];
        *(f32x4*)(S_ws + o + q * 4) = sv;
    }
}

// ---------------------------------------------------------------------------
// 3-level parallel chunk-combine. Thread = (b, grp, d, n).
__global__ __launch_bounds__(256) void combine_a(
    const float* __restrict__ sd_ws, const float* __restrict__ S_ws,
    const float* __restrict__ A_log,
    float* __restrict__ Sg, float* __restrict__ sdg)
{
    int idx = blockIdx.x * 256 + threadIdx.x;       // [0, BZ*NGRP*DD*NS)
    int n = idx & 15;
    int d = (idx >> 4) % DD;
    int grp = (idx >> 4) / DD % NGRP;
    int b = idx / (NS * DD * NGRP);
    float Av = -__expf(A_log[d * NS + n]);
    float h = 0.f, sds = 0.f;
    #pragma unroll
    for (int j = 0; j < GSZ; j++) {
        int g = grp * GSZ + j;
        size_t cb = (size_t)(b * NG + g) * DD + d;
        float sd = sd_ws[cb];
        float a = __expf(sd * Av);
        h = fmaf(a, h, S_ws[cb * NS + n]);
        sds += sd;
    }
    size_t o = (size_t)(b * NGRP + grp) * DD + d;
    Sg[o * NS + n] = h;
    if (n == 0) sdg[o] = sds;
}

__global__ __launch_bounds__(256) void combine_b(
    const float* __restrict__ Sg, const float* __restrict__ sdg,
    const float* __restrict__ A_log, float* __restrict__ Hgrp)
{
    int idx = blockIdx.x * 256 + threadIdx.x;       // [0, BZ*DD*NS)
    int n = idx & 15;
    int d = (idx >> 4) % DD;
    int b = idx / (NS * DD);
    float Av = -__expf(A_log[d * NS + n]);
    float h = 0.f;
    #pragma unroll
    for (int grp = 0; grp < NGRP; grp++) {
        size_t o = (size_t)(b * NGRP + grp) * DD + d;
        Hgrp[o * NS + n] = h;
        float a = __expf(sdg[o] * Av);
        h = fmaf(a, h, Sg[o * NS + n]);
    }
}

__global__ __launch_bounds__(256) void combine_c(
    const float* __restrict__ sd_ws, const float* __restrict__ S_ws,
    const float* __restrict__ Hgrp, const float* __restrict__ A_log,
    float* __restrict__ H_ws)
{
    int idx = blockIdx.x * 256 + threadIdx.x;       // [0, BZ*NGRP*DD*NS)
    int n = idx & 15;
    int d = (idx >> 4) % DD;
    int grp = (idx >> 4) / DD % NGRP;
    int b = idx / (NS * DD * NGRP);
    float Av = -__expf(A_log[d * NS + n]);
    float h = Hgrp[((size_t)(b * NGRP + grp) * DD + d) * NS + n];
    #pragma unroll
    for (int j = 0; j < GSZ; j++) {
        int g = grp * GSZ + j;
        size_t cb = (size_t)(b * NG + g) * DD + d;
        H_ws[cb * NS + n] = h;
        float a = __expf(sd_ws[cb] * Av);
        h = fmaf(a, h, S_ws[cb * NS + n]);
    }
}

// ---------------------------------------------------------------------------
__global__ __launch_bounds__(64) void scan_pass2(
    const _Float16* __restrict__ uh, const _Float16* __restrict__ ul,
    const float* __restrict__ dtb, const float* __restrict__ Bb,
    const float* __restrict__ Cb, const float* __restrict__ A_log,
    const float* __restrict__ dtw, const float* __restrict__ dtbias,
    const float* __restrict__ H_ws, const float* __restrict__ zs,
    const float* __restrict__ Dvec,
    _Float16* __restrict__ yh, _Float16* __restrict__ yl)
{
    int g = blockIdx.x, dblk = blockIdx.y, b = blockIdx.z;
    int d = dblk * 64 + threadIdx.x;
    size_t tbase = (size_t)b * LL + g * LC;
    float Av[NS];
    #pragma unroll
    for (int n = 0; n < NS; n++) Av[n] = -__expf(A_log[d * NS + n]);
    float w6[RR];
    #pragma unroll
    for (int r = 0; r < RR; r++) w6[r] = dtw[d * RR + r];
    float b2 = 2.f * dtbias[d];
    float h[NS];
    size_t o = ((size_t)(b * NG + g) * DD + d) * NS;
    #pragma unroll
    for (int q = 0; q < 4; q++) {
        f32x4 hv = *(const f32x4*)(H_ws + o + q * 4);
        #pragma unroll
        for (int e = 0; e < 4; e++) h[q * 4 + e] = hv[e];
    }
    float Dv = Dvec[d];
    const _Float16* uhp = uh + tbase * DD + d;
    const _Float16* ulp = ul + tbase * DD + d;
    const float* zp = zs + tbase * DD + d;
    _Float16* yhp = yh + tbase * DD + d;
    _Float16* ylp = yl + tbase * DD + d;
    #pragma unroll 2
    for (int t = 0; t < LC; t++) {
        f32x4 d0 = *(const f32x4*)&dtb[(tbase + t) * 8];
        f32x4 d1 = *(const f32x4*)&dtb[(tbase + t) * 8 + 4];
        float s = b2;
        s = fmaf(d0[0], w6[0], s); s = fmaf(d0[1], w6[1], s);
        s = fmaf(d0[2], w6[2], s); s = fmaf(d0[3], w6[3], s);
        s = fmaf(d1[0], w6[4], s); s = fmaf(d1[1], w6[5], s);
        float dlt = softplusf(s);
        float uu = ((float)uhp[(size_t)t * DD] + (float)ulp[(size_t)t * DD]) * (1.f / SA);
        float du = dlt * uu;
        f32x4 Bv[4], Cv[4];
        #pragma unroll
        for (int q = 0; q < 4; q++) {
            Bv[q] = *(const f32x4*)&Bb[(tbase + t) * 16 + q * 4];
            Cv[q] = *(const f32x4*)&Cb[(tbase + t) * 16 + q * 4];
        }
        float yv = 0.f;
        #pragma unroll
        for (int n = 0; n < NS; n++) {
            float a = __expf(dlt * Av[n]);
            h[n] = fmaf(a, h[n], du * Bv[n >> 2][n & 3]);
            yv = fmaf(h[n], Cv[n >> 2][n & 3], yv);
        }
        float zv = zp[(size_t)t * DD];
        float y = (yv + uu * Dv) * zv * SY;
        _Float16 hh = (_Float16)y;
        yhp[(size_t)t * DD] = hh;
        ylp[(size_t)t * DD] = (_Float16)(y - (float)hh);
    }
}

// ---------------------------------------------------------------------------
extern "C" void kernel_launch(void* const* d_in, const int* in_sizes, int n_in,
                              void* d_out, int out_size, void* d_ws, size_t ws_size,
                              hipStream_t stream)
{
    (void)in_sizes; (void)n_in; (void)out_size; (void)ws_size;
    const float* x        = (const float*)d_in[0];
    const float* K        = (const float*)d_in[1];
    const float* Q        = (const float*)d_in[2];
    const float* in_projw = (const float*)d_in[3];
    const float* conv_w   = (const float*)d_in[4];
    const float* conv_b   = (const float*)d_in[5];
    const float* k_ln_g   = (const float*)d_in[6];
    const float* k_ln_b   = (const float*)d_in[7];
    const float* k_w      = (const float*)d_in[8];
    const float* k_b      = (const float*)d_in[9];
    const float* q_ln_g   = (const float*)d_in[10];
    const float* q_ln_b   = (const float*)d_in[11];
    const float* q_w      = (const float*)d_in[12];
    const float* q_b      = (const float*)d_in[13];
    const float* dtbc_w   = (const float*)d_in[14];
    const float* dt_w     = (const float*)d_in[15];
    const float* dt_b     = (const float*)d_in[16];
    const float* gate_w   = (const float*)d_in[17];
    const float* gate_b   = (const float*)d_in[18];
    const float* A_log    = (const float*)d_in[19];
    const float* Dvec     = (const float*)d_in[20];
    const float* out_w    = (const float*)d_in[21];
    float* out = (float*)d_out;

    const size_t S0 = (size_t)MTOK * DD;
    char* base = (char*)d_ws;
    size_t off = 0;
    auto alloc = [&](size_t bytes) {
        char* p = base + off;
        off += (bytes + 255) & ~(size_t)255;
        return p;
    };
    float*     xin   = (float*)alloc(S0 * 4);            // reused as zs
    _Float16*  uH    = (_Float16*)alloc(S0 * 2);
    _Float16*  uL    = (_Float16*)alloc(S0 * 2);
    _Float16*  KpH   = (_Float16*)alloc(S0 * 2);         // reused as yH
    _Float16*  KpL   = (_Float16*)alloc(S0 * 2);         // reused as yL
    _Float16*  QpH   = (_Float16*)alloc(S0 * 2);
    _Float16*  QpL   = (_Float16*)alloc(S0 * 2);
    float*     dtbB  = (float*)alloc((size_t)MTOK * 8 * 4);
    float*     Bb    = (float*)alloc((size_t)MTOK * 16 * 4);
    float*     Cb    = (float*)alloc((size_t)MTOK * 16 * 4);
    float*     gwK   = (float*)alloc(DD * CD * 4);
    float*     gwQ   = (float*)alloc(DD * CD * 4);
    float*     wsumK = (float*)alloc(DD * 4);
    float*     biasK = (float*)alloc(DD * 4);
    float*     wsumQ = (float*)alloc(DD * 4);
    float*     biasQ = (float*)alloc(DD * 4);
    _Float16*  ipWh  = (_Float16*)alloc(DD * CD * 2);
    _Float16*  ipWl  = (_Float16*)alloc(DD * CD * 2);
    _Float16*  kWh   = (_Float16*)alloc(DD * CD * 2);
    _Float16*  kWl   = (_Float16*)alloc(DD * CD * 2);
    _Float16*  qWh   = (_Float16*)alloc(DD * CD * 2);
    _Float16*  qWl   = (_Float16*)alloc(DD * CD * 2);
    _Float16*  dbWh  = (_Float16*)alloc(48 * 384 * 2);
    _Float16*  dbWl  = (_Float16*)alloc(48 * 384 * 2);
    _Float16*  gWh   = (_Float16*)alloc(DD * 384 * 2);
    _Float16*  gWl   = (_Float16*)alloc(DD * 384 * 2);
    _Float16*  oWh   = (_Float16*)alloc(96 * DD * 2);
    _Float16*  oWl   = (_Float16*)alloc(96 * DD * 2);
    float*     sd_ws = (float*)alloc((size_t)BZ * NG * DD * 4);
    float*     S_ws  = (float*)alloc((size_t)BZ * NG * DD * NS * 4);
    float*     H_ws  = (float*)alloc((size_t)BZ * NG * DD * NS * 4);
    float*     Sg    = (float*)alloc((size_t)BZ * NGRP * DD * NS * 4);
    float*     sdg   = (float*)alloc((size_t)BZ * NGRP * DD * 4);
    float*     Hgrp  = (float*)alloc((size_t)BZ * NGRP * DD * NS * 4);
    float*    zs = xin;
    _Float16* yH = KpH;
    _Float16* yL = KpL;

    prep_kernel<<<dim3(DD, 2), 96, 0, stream>>>(k_ln_g, k_ln_b, k_w, k_b,
        q_ln_g, q_ln_b, q_w, q_b, gwK, wsumK, biasK, gwQ, wsumQ, biasQ);
    {
        const int total = 18432 * 5 + 73728;
        split_all_kernel<<<(total + 255) / 256, 256, 0, stream>>>(
            in_projw, gwK, gwQ, dtbc_w, gate_w, out_w,
            ipWh, ipWl, kWh, kWl, qWh, qWl, dbWh, dbWl, gWh, gWl, oWh, oWl);
    }

    mfma_projCH3<<<dim3(LL / 64, BZ, 3), 256, 0, stream>>>(
        x, K, Q, ipWh, ipWl, kWh, kWl, qWh, qWl,
        wsumK, biasK, wsumQ, biasQ, xin, KpH, KpL, QpH, QpL);
    conv_kernel<<<(MTOK / 4) * (DD / 4) / 256, 256, 0, stream>>>(xin, conv_w, conv_b, uH, uL);
    gemm_zx<<<(MTOK / 64) * 2 + MTOK / 128, 256, 0, stream>>>(
        uH, uL, QpH, QpL, KpH, KpL, gWh, gWl, dbWh, dbWl, gate_b,
        zs, dtbB, Bb, Cb);
    scan_pass1<<<dim3(NG, DD / 64, BZ), 64, 0, stream>>>(
        uH, uL, dtbB, Bb, A_log, dt_w, dt_b, sd_ws, S_ws);
    combine_a<<<(BZ * NGRP * DD * NS) / 256, 256, 0, stream>>>(sd_ws, S_ws, A_log, Sg, sdg);
    combine_b<<<(BZ * DD * NS) / 256, 256, 0, stream>>>(Sg, sdg, A_log, Hgrp);
    combine_c<<<(BZ * NGRP * DD * NS) / 256, 256, 0, stream>>>(sd_ws, S_ws, Hgrp, A_log, H_ws);
    scan_pass2<<<dim3(NG, DD / 64, BZ), 64, 0, stream>>>(
        uH, uL, dtbB, Bb, Cb, A_log, dt_w, dt_b, H_ws, zs, Dvec, yH, yL);
    gemm_out<<<MTOK / 64, 256, 0, stream>>>(yH, yL, oWh, oWl, out);
}